// Round 7
// baseline (116.204 us; speedup 1.0000x reference)
//
#include <hip/hip_runtime.h>

#define Bn 16
#define Cn 256
#define HWn 9216
#define Pn 64
#define HEADSn 4
#define Gn 2304
#define STILE 64
#define TILES_PER_B (HWn / STILE)    // 144
#define NBLK (Bn * TILES_PER_B)      // 2304

typedef float f32x4 __attribute__((ext_vector_type(4)));
typedef short short4v __attribute__((ext_vector_type(4)));
typedef short short8 __attribute__((ext_vector_type(8)));

static __device__ __forceinline__ unsigned short f2bf(float f) {
    unsigned int b = __builtin_bit_cast(unsigned int, f);
    unsigned int r = b + 0x7FFFu + ((b >> 16) & 1u);   // RNE
    return (unsigned short)(r >> 16);
}
static __device__ __forceinline__ float bf2f(unsigned short u) {
    unsigned int b = ((unsigned int)u) << 16;
    return __builtin_bit_cast(float, b);
}

// ---- K0: scbc fold + w1 -> bf16 plain row-major [64][256] in ws ----
__global__ __launch_bounds__(256)
void k0_prep(const float* __restrict__ w1, const float* __restrict__ b1,
             const float* __restrict__ gamma, const float* __restrict__ beta,
             const float* __restrict__ mean, const float* __restrict__ var,
             float* __restrict__ scbc, short* __restrict__ w1b)
{
    const int gid = blockIdx.x * 256 + threadIdx.x;
    if (gid < 2048) {                       // 2048 granules of 8 floats
        const float* p = w1 + gid * 8;
        short8 v;
        #pragma unroll
        for (int j = 0; j < 8; ++j) v[j] = (short)f2bf(p[j]);
        *reinterpret_cast<short8*>(&w1b[gid * 8]) = v;
    }
    if (gid < Pn) {
        float s = gamma[gid] * rsqrtf(var[gid] + 1e-5f);
        scbc[gid] = s;
        scbc[Pn + gid] = (b1[gid] - mean[gid]) * s + beta[gid];
    }
}

// ---- K1: GEMM1 + BN/ReLU -> hm partials + h materialized as [b][s][p] bf16 ----
// A-fragments straight from L2-resident w1b (no w1 LDS tile) -> 33 KB LDS, 4 blk/CU
__global__ __launch_bounds__(256, 4)
void k1_gemm(const float* __restrict__ x, const short* __restrict__ w1b,
             const float* __restrict__ scbc, const float* __restrict__ wm,
             float* __restrict__ hmp, short* __restrict__ hg)
{
    __shared__ short xl[Cn * STILE];  // 32 KB bf16 x tile, swizzled; reused as ht[64][72]
    __shared__ float hml[Pn];

    const int bid  = blockIdx.x;
    const int b    = bid / TILES_PER_B;
    const int tile = bid % TILES_PER_B;
    const int s0   = tile * STILE;
    const int t    = threadIdx.x;
    const int lane = t & 63;
    const int wv   = t >> 6;
    const int g    = lane >> 4;
    const int m16  = lane & 15;
    const int sbase = wv * 16 + m16;

    // ---- x: DENSE loads: 16-lane group reads a full 256B row segment/instr ----
    const int c0 = t >> 4;                              // 0..15
    const int s4 = t & 15;                              // 0..15
    const float* xb = x + (size_t)b * Cn * HWn + s0 + s4 * 4;
    f32x4 xa[16];
    #pragma unroll
    for (int i = 0; i < 16; ++i)
        xa[i] = *reinterpret_cast<const f32x4*>(xb + (size_t)(c0 + 16 * i) * HWn);

    if (t < Pn) hml[t] = 0.f;

    // ---- convert + swizzled LDS write (4-elem/8B granules) ----
    // elem(c,s) -> (c*64+s) ^ (f(c)<<3), f(c) = (c&7)^((c>>3)&3)
    #pragma unroll
    for (int i = 0; i < 16; ++i) {
        const int c = c0 + 16 * i;
        short4v v;
        #pragma unroll
        for (int j = 0; j < 4; ++j) v[j] = (short)f2bf(xa[i][j]);
        const int f   = (c & 7) ^ ((c >> 3) & 3);
        const int idx = (c * STILE + s4 * 4) ^ (f << 3);
        *reinterpret_cast<short4v*>(&xl[idx]) = v;
    }
    __syncthreads();

    // ---- GEMM1: D[p][s] = sum_c w1[p][c]*x[c][s], bf16 MFMA 16x16x32 ----
    f32x4 acc[4] = { {0,0,0,0}, {0,0,0,0}, {0,0,0,0}, {0,0,0,0} };
    #pragma unroll
    for (int ks = 0; ks < 8; ++ks) {
        short8 bf;
        #pragma unroll
        for (int j = 0; j < 8; ++j) {                  // k=ks*32+g*8+j: f(k)=j^g
            const int k = ks * 32 + g * 8 + j;
            bf[j] = xl[(k * STILE + sbase) ^ ((j ^ g) << 3)];
        }
        #pragma unroll
        for (int rt = 0; rt < 4; ++rt) {
            const int row = rt * 16 + m16;
            const short8 af = *reinterpret_cast<const short8*>(
                w1b + row * Cn + ks * 32 + g * 8);     // L2-hot, 64B-line-dense
            acc[rt] = __builtin_amdgcn_mfma_f32_16x16x32_bf16(af, bf, acc[rt], 0, 0, 0);
        }
    }

    // ---- BN + ReLU (C/D: col=lane&15 -> s, row=(lane>>4)*4+reg -> p_local) ----
    float h[4][4];
    #pragma unroll
    for (int rt = 0; rt < 4; ++rt) {
        #pragma unroll
        for (int r = 0; r < 4; ++r) {
            const int p = rt * 16 + g * 4 + r;
            const float hv = acc[rt][r] * scbc[p] + scbc[Pn + p];
            h[rt][r] = hv > 0.f ? hv : 0.f;
        }
    }

    // ---- hm partials: block-local LDS reduce, no global atomics ----
    const float wmv = wm[s0 + sbase];
    #pragma unroll
    for (int rt = 0; rt < 4; ++rt) {
        #pragma unroll
        for (int r = 0; r < 4; ++r) {
            float v = h[rt][r] * wmv;
            v += __shfl_xor(v, 1); v += __shfl_xor(v, 2);
            v += __shfl_xor(v, 4); v += __shfl_xor(v, 8);
            if (m16 == 0) atomicAdd(&hml[rt * 16 + g * 4 + r], v);   // LDS atomic
        }
    }
    __syncthreads();   // xl B-reads done everywhere + hml complete

    // ---- transpose h into ht[s][p] (reuse xl; pad row to 72 shorts) ----
    short* ht = xl;
    #pragma unroll
    for (int rt = 0; rt < 4; ++rt) {
        short4v hv;
        #pragma unroll
        for (int r = 0; r < 4; ++r) hv[r] = (short)f2bf(h[rt][r]);
        *reinterpret_cast<short4v*>(&ht[sbase * 72 + rt * 16 + g * 4]) = hv;
    }
    __syncthreads();

    // ---- coalesced h store: [64 s][64 p] -> hg[(b*HW + s0+s)*64 + p] ----
    {
        const int s = t >> 2, q = t & 3;
        const short8 a0 = *reinterpret_cast<const short8*>(&ht[s * 72 + q * 16]);
        const short8 a1 = *reinterpret_cast<const short8*>(&ht[s * 72 + q * 16 + 8]);
        short* dst = hg + ((size_t)b * HWn + s0 + s) * Pn + q * 16;
        *reinterpret_cast<short8*>(dst)     = a0;
        *reinterpret_cast<short8*>(dst + 8) = a1;
    }
    if (t < Pn) hmp[bid * Pn + t] = hml[t];
}

// ---- K2: reduce hm partials -> logits -> softmax -> wmix/bmix ----
__global__ __launch_bounds__(256)
void k2_mask(const float* __restrict__ hmp, const float* __restrict__ w2,
             const float* __restrict__ b2, const float* __restrict__ wm,
             float* __restrict__ wmix, float* __restrict__ bmix)
{
    __shared__ float hms[Pn];
    __shared__ float masks[Cn];
    __shared__ float red[4];
    __shared__ float part[4][Pn];

    const int bh = blockIdx.x;
    const int head = bh & (HEADSn - 1);
    const int t = threadIdx.x;
    const int l = t & 63;
    const int wv = t >> 6;

    // reduce 36 per-block partials for this (b,head)
    {
        const int p = t & 63, q = t >> 6;
        const float* base = hmp + ((size_t)(bh >> 2) * TILES_PER_B + (bh & 3) * 36) * Pn;
        float sp = 0.f;
        #pragma unroll
        for (int j = 0; j < 9; ++j) sp += base[(q + 4 * j) * Pn + p];
        part[q][p] = sp;
    }
    __syncthreads();
    if (t < Pn) hms[t] = part[0][t] + part[1][t] + part[2][t] + part[3][t];
    __syncthreads();

    // wmsum over this head's group
    float wsum = 0.f;
    for (int i = t; i < Gn; i += 256) wsum += wm[head * Gn + i];
    #pragma unroll
    for (int d = 1; d < 64; d <<= 1) wsum += __shfl_xor(wsum, d);
    if (l == 0) red[wv] = wsum;
    __syncthreads();
    wsum = red[0] + red[1] + red[2] + red[3];

    // logits[c] = sum_k w2[c,k]*hm[k] + b2[c]*wsum
    float lg = 0.f;
    #pragma unroll
    for (int k = 0; k < Pn; ++k) lg = fmaf(w2[t * Pn + k], hms[k], lg);
    lg = fmaf(b2[t], wsum, lg);

    // softmax over 256 channels
    float mx = lg;
    #pragma unroll
    for (int d = 1; d < 64; d <<= 1) mx = fmaxf(mx, __shfl_xor(mx, d));
    __syncthreads();
    if (l == 0) red[wv] = mx;
    __syncthreads();
    mx = fmaxf(fmaxf(red[0], red[1]), fmaxf(red[2], red[3]));
    const float ev = __expf(lg - mx);
    float sm = ev;
    #pragma unroll
    for (int d = 1; d < 64; d <<= 1) sm += __shfl_xor(sm, d);
    __syncthreads();
    if (l == 0) red[wv] = sm;
    __syncthreads();
    sm = red[0] + red[1] + red[2] + red[3];
    masks[t] = ev / sm;
    __syncthreads();

    // wmix[k] = sum_c mask[c]*w2[c,k]
    {
        const int k = t & (Pn - 1);
        const int q = t >> 6;
        float wp = 0.f;
        #pragma unroll
        for (int i = 0; i < 64; ++i) {
            const int c = q * 64 + i;
            wp = fmaf(masks[c], w2[c * Pn + k], wp);
        }
        part[q][k] = wp;
    }
    __syncthreads();
    if (t < Pn) wmix[bh * Pn + t] = part[0][t] + part[1][t] + part[2][t] + part[3][t];

    // bmix = sum_c mask[c]*b2[c]
    float bp = masks[t] * b2[t];
    #pragma unroll
    for (int d = 1; d < 64; d <<= 1) bp += __shfl_xor(bp, d);
    __syncthreads();
    if (l == 0) red[wv] = bp;
    __syncthreads();
    if (t == 0) bmix[bh] = red[0] + red[1] + red[2] + red[3];
}

// ---- K3: pure streaming: ctx[s] = wmix . h[s,:]; out = x + ctx ----
__global__ __launch_bounds__(256)
void k3_stream(const float* __restrict__ x, const short* __restrict__ hg,
               const float* __restrict__ wmix, const float* __restrict__ bmix,
               float* __restrict__ out)
{
    __shared__ float ctxl[STILE];

    const int bid  = blockIdx.x;
    const int b    = bid / TILES_PER_B;
    const int tile = bid % TILES_PER_B;
    const int s0   = tile * STILE;
    const int head = s0 / Gn;
    const int bh   = b * HEADSn + head;
    const int t    = threadIdx.x;

    if (t < STILE) {
        const short* hr = hg + ((size_t)b * HWn + s0 + t) * Pn;   // dense 128 B/lane
        const float* wmx = wmix + bh * Pn;
        float acc = 0.f;
        #pragma unroll
        for (int i = 0; i < 8; ++i) {
            const short8 v = *reinterpret_cast<const short8*>(hr + i * 8);
            const f32x4 w0 = *reinterpret_cast<const f32x4*>(wmx + i * 8);
            const f32x4 w1v = *reinterpret_cast<const f32x4*>(wmx + i * 8 + 4);
            #pragma unroll
            for (int j = 0; j < 4; ++j) {
                acc = fmaf(bf2f((unsigned short)v[j]), w0[j], acc);
                acc = fmaf(bf2f((unsigned short)v[4 + j]), w1v[j], acc);
            }
        }
        ctxl[t] = acc + bmix[bh];
    }
    __syncthreads();

    const int c0 = t >> 4;
    const int s4 = t & 15;
    const f32x4 cv = *reinterpret_cast<const f32x4*>(&ctxl[s4 * 4]);
    const float* xb = x + (size_t)b * Cn * HWn + s0 + s4 * 4;
    float* ob = out + (size_t)b * Cn * HWn + s0 + s4 * 4;
    #pragma unroll
    for (int i = 0; i < 16; ++i) {
        const size_t off = (size_t)(c0 + 16 * i) * HWn;
        *reinterpret_cast<f32x4*>(ob + off) =
            *reinterpret_cast<const f32x4*>(xb + off) + cv;
    }
}

extern "C" void kernel_launch(void* const* d_in, const int* in_sizes, int n_in,
                              void* d_out, int out_size, void* d_ws, size_t ws_size,
                              hipStream_t stream)
{
    (void)in_sizes; (void)n_in; (void)out_size; (void)ws_size;
    const float* x     = (const float*)d_in[0];
    const float* w1    = (const float*)d_in[1];
    const float* b1    = (const float*)d_in[2];
    const float* gamma = (const float*)d_in[3];
    const float* beta  = (const float*)d_in[4];
    const float* mean  = (const float*)d_in[5];
    const float* var   = (const float*)d_in[6];
    const float* w2    = (const float*)d_in[7];
    const float* b2    = (const float*)d_in[8];
    const float* wm    = (const float*)d_in[9];
    // d_in[10] = bm: constant over softmax axis -> dropped

    float* out  = (float*)d_out;
    float* wsf  = (float*)d_ws;
    float* hmp  = wsf;                            // [2304*64] f32
    float* wmix = hmp + NBLK * Pn;                // [64*64]
    float* bmix = wmix + Bn * HEADSn * Pn;        // [64]
    float* scbc = bmix + 64;                      // [128]
    short* w1b  = (short*)(scbc + 128);           // [64*256] bf16 plain row-major
    short* hg   = w1b + Pn * Cn;                  // [16*9216*64] bf16, after w1b

    k0_prep<<<dim3(8), dim3(256), 0, stream>>>(w1, b1, gamma, beta, mean, var, scbc, w1b);
    k1_gemm<<<dim3(NBLK), dim3(256), 0, stream>>>(x, w1b, scbc, wm, hmp, hg);
    k2_mask<<<dim3(Bn * HEADSn), dim3(256), 0, stream>>>(hmp, w2, b2, wm, wmix, bmix);
    k3_stream<<<dim3(NBLK), dim3(256), 0, stream>>>(x, hg, wmix, bmix, out);
}

// Round 8
// 101.610 us; speedup vs baseline: 1.1436x; 1.1436x over previous
//
#include <hip/hip_runtime.h>

#define Bn 16
#define Cn 256
#define HWn 9216
#define Pn 64
#define HEADSn 4
#define Gn 2304
#define STILE 64
#define TILES_PER_B (HWn / STILE)    // 144
#define NTILE (Bn * TILES_PER_B)     // 2304
#define CHUNK 9                      // tiles per persistent block
#define NBLK (NTILE / CHUNK)         // 256 blocks, 1 per CU

typedef float f32x4 __attribute__((ext_vector_type(4)));
typedef short short4v __attribute__((ext_vector_type(4)));
typedef short short8 __attribute__((ext_vector_type(8)));

static __device__ __forceinline__ unsigned short f2bf(float f) {
    unsigned int b = __builtin_bit_cast(unsigned int, f);
    unsigned int r = b + 0x7FFFu + ((b >> 16) & 1u);   // RNE
    return (unsigned short)(r >> 16);
}
static __device__ __forceinline__ float bf2f(unsigned short u) {
    unsigned int b = ((unsigned int)u) << 16;
    return __builtin_bit_cast(float, b);
}
static __device__ __forceinline__ void gload_lds16(const void* g, void* l) {
    __builtin_amdgcn_global_load_lds((const __attribute__((address_space(1))) void*)g,
                                     (__attribute__((address_space(3))) void*)l, 16, 0, 0);
}

// ---- K0: scbc fold + w1 -> bf16 PRE-SWIZZLED into ws (round-6 version) ----
__global__ __launch_bounds__(256)
void k0_prep(const float* __restrict__ w1, const float* __restrict__ b1,
             const float* __restrict__ gamma, const float* __restrict__ beta,
             const float* __restrict__ mean, const float* __restrict__ var,
             float* __restrict__ scbc, short* __restrict__ w1s)
{
    const int gid = blockIdx.x * 256 + threadIdx.x;
    if (gid < 2048) {                       // 2048 granules of 8 floats
        const int row = gid >> 5;
        const int kc  = (gid & 31) << 3;
        const float* p = w1 + row * Cn + kc;
        short8 v;
        #pragma unroll
        for (int j = 0; j < 8; ++j) v[j] = (short)f2bf(p[j]);
        const int idx = (row * Cn + kc) ^ ((row & 7) << 3);
        *reinterpret_cast<short8*>(&w1s[idx]) = v;
    }
    if (gid < Pn) {
        float s = gamma[gid] * rsqrtf(var[gid] + 1e-5f);
        scbc[gid] = s;
        scbc[Pn + gid] = (b1[gid] - mean[gid]) * s + beta[gid];
    }
}

// ---- K1: persistent, double-buffered. 9 tiles/block, one (b,head) per block. ----
__global__ __launch_bounds__(256)
void k1_gemm(const float* __restrict__ x, const short* __restrict__ w1s,
             const float* __restrict__ scbc, const float* __restrict__ wm,
             float* __restrict__ hmp, short* __restrict__ hg)
{
    __shared__ short w1l[Pn * Cn];        // 32 KB, staged once via global_load_lds
    __shared__ short xl[2][Cn * STILE];   // 2 x 32 KB double-buffered x tile
    __shared__ float hml[4][Pn];          // 1 KB wave-combine for hm

    const int pid  = blockIdx.x;           // 0..255
    const int b    = pid / 16;             // (pid*9)/144
    const int t0b  = pid * CHUNK - b * TILES_PER_B;  // first tile within batch
    const int t    = threadIdx.x;
    const int lane = t & 63;
    const int wv   = t >> 6;
    const int g    = lane >> 4;
    const int m16  = lane & 15;
    const int sbase = wv * 16 + m16;

    // ---- w1: async LDS copy, once per block ----
    #pragma unroll
    for (int i = 0; i < 8; ++i) {
        const int chunk = i * 4 + wv;                   // wave-uniform
        gload_lds16(w1s + chunk * 512 + lane * 8, &w1l[chunk * 512]);
    }

    const int c0 = t >> 4;                              // 0..15
    const int s4 = t & 15;                              // 0..15
    const float* xbb = x + (size_t)b * Cn * HWn + s4 * 4;
    short* hgb = hg + (size_t)b * HWn * Pn;
    const float* scp = scbc;

    // BN constants for this lane's 16 p-values (hoisted out of the tile loop)
    float sc[4][4], bc[4][4];
    #pragma unroll
    for (int rt = 0; rt < 4; ++rt)
        #pragma unroll
        for (int r = 0; r < 4; ++r) {
            const int p = rt * 16 + g * 4 + r;
            sc[rt][r] = scp[p];
            bc[rt][r] = scp[Pn + p];
        }

    float hmacc[4][4];
    #pragma unroll
    for (int rt = 0; rt < 4; ++rt)
        #pragma unroll
        for (int r = 0; r < 4; ++r) hmacc[rt][r] = 0.f;

    // ---- prologue: load + stage tile 0 ----
    {
        const float* xb = xbb + (size_t)(t0b * STILE);
        f32x4 xa[16];
        #pragma unroll
        for (int i = 0; i < 16; ++i)
            xa[i] = *reinterpret_cast<const f32x4*>(xb + (size_t)(c0 + 16 * i) * HWn);
        #pragma unroll
        for (int i = 0; i < 16; ++i) {
            const int c = c0 + 16 * i;
            short4v v;
            #pragma unroll
            for (int j = 0; j < 4; ++j) v[j] = (short)f2bf(xa[i][j]);
            const int f   = (c & 7) ^ ((c >> 3) & 3);
            const int idx = (c * STILE + s4 * 4) ^ (f << 3);
            *reinterpret_cast<short4v*>(&xl[0][idx]) = v;
        }
    }
    __syncthreads();    // w1l + xl[0] ready

    int cur = 0;
    for (int it = 0; it < CHUNK; ++it) {
        const int s0 = (t0b + it) * STILE;

        // ---- issue next tile's loads EARLY (hidden under MFMA) ----
        f32x4 xn[16];
        if (it < CHUNK - 1) {
            const float* xb = xbb + (size_t)(s0 + STILE);
            #pragma unroll
            for (int i = 0; i < 16; ++i)
                xn[i] = *reinterpret_cast<const f32x4*>(xb + (size_t)(c0 + 16 * i) * HWn);
        }

        // ---- GEMM1 on xl[cur]: D[p][s] = sum_c w1[p][c]*x[c][s] ----
        const short* xc = xl[cur];
        f32x4 acc[4] = { {0,0,0,0}, {0,0,0,0}, {0,0,0,0}, {0,0,0,0} };
        #pragma unroll
        for (int ks = 0; ks < 8; ++ks) {
            short8 bf;
            #pragma unroll
            for (int j = 0; j < 8; ++j) {              // k=ks*32+g*8+j: f(k)=j^g
                const int k = ks * 32 + g * 8 + j;
                bf[j] = xc[(k * STILE + sbase) ^ ((j ^ g) << 3)];
            }
            #pragma unroll
            for (int rt = 0; rt < 4; ++rt) {
                const int row = rt * 16 + m16;
                const int idx = (row * Cn + ks * 32 + g * 8) ^ ((row & 7) << 3);
                const short8 af = *reinterpret_cast<const short8*>(&w1l[idx]);
                acc[rt] = __builtin_amdgcn_mfma_f32_16x16x32_bf16(af, bf, acc[rt], 0, 0, 0);
            }
        }

        // ---- BN + ReLU, hm register-accumulate, direct h store ----
        const float wmv = wm[s0 + sbase];
        short* hrow = hgb + (size_t)(s0 + sbase) * Pn;
        #pragma unroll
        for (int rt = 0; rt < 4; ++rt) {
            short4v hv;
            #pragma unroll
            for (int r = 0; r < 4; ++r) {
                float h = acc[rt][r] * sc[rt][r] + bc[rt][r];
                h = h > 0.f ? h : 0.f;
                hmacc[rt][r] = fmaf(h, wmv, hmacc[rt][r]);
                hv[r] = (short)f2bf(h);
            }
            *reinterpret_cast<short4v*>(hrow + rt * 16 + g * 4) = hv;
        }

        // ---- stage next tile into the other buffer ----
        if (it < CHUNK - 1) {
            #pragma unroll
            for (int i = 0; i < 16; ++i) {
                const int c = c0 + 16 * i;
                short4v v;
                #pragma unroll
                for (int j = 0; j < 4; ++j) v[j] = (short)f2bf(xn[i][j]);
                const int f   = (c & 7) ^ ((c >> 3) & 3);
                const int idx = (c * STILE + s4 * 4) ^ (f << 3);
                *reinterpret_cast<short4v*>(&xl[cur ^ 1][idx]) = v;
            }
            __syncthreads();
            cur ^= 1;
        }
    }

    // ---- final hm reduce: shfl over the 16 m16-lanes, combine 4 waves in LDS ----
    #pragma unroll
    for (int rt = 0; rt < 4; ++rt)
        #pragma unroll
        for (int r = 0; r < 4; ++r) {
            float v = hmacc[rt][r];
            v += __shfl_xor(v, 1); v += __shfl_xor(v, 2);
            v += __shfl_xor(v, 4); v += __shfl_xor(v, 8);
            hmacc[rt][r] = v;
        }
    if (m16 == 0) {
        #pragma unroll
        for (int rt = 0; rt < 4; ++rt) {
            f32x4 hv = { hmacc[rt][0], hmacc[rt][1], hmacc[rt][2], hmacc[rt][3] };
            *reinterpret_cast<f32x4*>(&hml[wv][rt * 16 + g * 4]) = hv;
        }
    }
    __syncthreads();
    if (t < Pn) hmp[pid * Pn + t] = hml[0][t] + hml[1][t] + hml[2][t] + hml[3][t];
}

// ---- K2: reduce 4 block-partials -> logits -> softmax -> wmix/bmix ----
__global__ __launch_bounds__(256)
void k2_mask(const float* __restrict__ hmp, const float* __restrict__ w2,
             const float* __restrict__ b2, const float* __restrict__ wm,
             float* __restrict__ wmix, float* __restrict__ bmix)
{
    __shared__ float hms[Pn];
    __shared__ float masks[Cn];
    __shared__ float red[4];
    __shared__ float part[4][Pn];

    const int bh = blockIdx.x;
    const int head = bh & (HEADSn - 1);
    const int t = threadIdx.x;
    const int l = t & 63;
    const int wv = t >> 6;

    // blocks bh*4 .. bh*4+3 hold this (b,head)'s partials
    {
        const int p = t & 63, q = t >> 6;
        part[q][p] = hmp[(bh * 4 + q) * Pn + p];
    }
    __syncthreads();
    if (t < Pn) hms[t] = part[0][t] + part[1][t] + part[2][t] + part[3][t];
    __syncthreads();

    // wmsum over this head's group
    float wsum = 0.f;
    for (int i = t; i < Gn; i += 256) wsum += wm[head * Gn + i];
    #pragma unroll
    for (int d = 1; d < 64; d <<= 1) wsum += __shfl_xor(wsum, d);
    if (l == 0) red[wv] = wsum;
    __syncthreads();
    wsum = red[0] + red[1] + red[2] + red[3];

    // logits[c] = sum_k w2[c,k]*hm[k] + b2[c]*wsum
    float lg = 0.f;
    #pragma unroll
    for (int k = 0; k < Pn; ++k) lg = fmaf(w2[t * Pn + k], hms[k], lg);
    lg = fmaf(b2[t], wsum, lg);

    // softmax over 256 channels
    float mx = lg;
    #pragma unroll
    for (int d = 1; d < 64; d <<= 1) mx = fmaxf(mx, __shfl_xor(mx, d));
    __syncthreads();
    if (l == 0) red[wv] = mx;
    __syncthreads();
    mx = fmaxf(fmaxf(red[0], red[1]), fmaxf(red[2], red[3]));
    const float ev = __expf(lg - mx);
    float sm = ev;
    #pragma unroll
    for (int d = 1; d < 64; d <<= 1) sm += __shfl_xor(sm, d);
    __syncthreads();
    if (l == 0) red[wv] = sm;
    __syncthreads();
    sm = red[0] + red[1] + red[2] + red[3];
    masks[t] = ev / sm;
    __syncthreads();

    // wmix[k] = sum_c mask[c]*w2[c,k]
    {
        const int k = t & (Pn - 1);
        const int q = t >> 6;
        float wp = 0.f;
        #pragma unroll
        for (int i = 0; i < 64; ++i) {
            const int c = q * 64 + i;
            wp = fmaf(masks[c], w2[c * Pn + k], wp);
        }
        part[q][k] = wp;
    }
    __syncthreads();
    if (t < Pn) wmix[bh * Pn + t] = part[0][t] + part[1][t] + part[2][t] + part[3][t];

    // bmix = sum_c mask[c]*b2[c]
    float bp = masks[t] * b2[t];
    #pragma unroll
    for (int d = 1; d < 64; d <<= 1) bp += __shfl_xor(bp, d);
    __syncthreads();
    if (l == 0) red[wv] = bp;
    __syncthreads();
    if (t == 0) bmix[bh] = red[0] + red[1] + red[2] + red[3];
}

// ---- K3: pure streaming: ctx[s] = wmix . h[s,:]; out = x + ctx ----
__global__ __launch_bounds__(256)
void k3_stream(const float* __restrict__ x, const short* __restrict__ hg,
               const float* __restrict__ wmix, const float* __restrict__ bmix,
               float* __restrict__ out)
{
    __shared__ float ctxl[STILE];

    const int bid  = blockIdx.x;
    const int b    = bid / TILES_PER_B;
    const int tile = bid % TILES_PER_B;
    const int s0   = tile * STILE;
    const int head = s0 / Gn;
    const int bh   = b * HEADSn + head;
    const int t    = threadIdx.x;

    if (t < STILE) {
        const short* hr = hg + ((size_t)b * HWn + s0 + t) * Pn;   // dense 128 B/lane
        const float* wmx = wmix + bh * Pn;
        float acc = 0.f;
        #pragma unroll
        for (int i = 0; i < 8; ++i) {
            const short8 v = *reinterpret_cast<const short8*>(hr + i * 8);
            const f32x4 w0 = *reinterpret_cast<const f32x4*>(wmx + i * 8);
            const f32x4 w1v = *reinterpret_cast<const f32x4*>(wmx + i * 8 + 4);
            #pragma unroll
            for (int j = 0; j < 4; ++j) {
                acc = fmaf(bf2f((unsigned short)v[j]), w0[j], acc);
                acc = fmaf(bf2f((unsigned short)v[4 + j]), w1v[j], acc);
            }
        }
        ctxl[t] = acc + bmix[bh];
    }
    __syncthreads();

    const int c0 = t >> 4;
    const int s4 = t & 15;
    const f32x4 cv = *reinterpret_cast<const f32x4*>(&ctxl[s4 * 4]);
    const float* xb = x + (size_t)b * Cn * HWn + s0 + s4 * 4;
    float* ob = out + (size_t)b * Cn * HWn + s0 + s4 * 4;
    #pragma unroll
    for (int i = 0; i < 16; ++i) {
        const size_t off = (size_t)(c0 + 16 * i) * HWn;
        *reinterpret_cast<f32x4*>(ob + off) =
            *reinterpret_cast<const f32x4*>(xb + off) + cv;
    }
}

extern "C" void kernel_launch(void* const* d_in, const int* in_sizes, int n_in,
                              void* d_out, int out_size, void* d_ws, size_t ws_size,
                              hipStream_t stream)
{
    (void)in_sizes; (void)n_in; (void)out_size; (void)ws_size;
    const float* x     = (const float*)d_in[0];
    const float* w1    = (const float*)d_in[1];
    const float* b1    = (const float*)d_in[2];
    const float* gamma = (const float*)d_in[3];
    const float* beta  = (const float*)d_in[4];
    const float* mean  = (const float*)d_in[5];
    const float* var   = (const float*)d_in[6];
    const float* w2    = (const float*)d_in[7];
    const float* b2    = (const float*)d_in[8];
    const float* wm    = (const float*)d_in[9];
    // d_in[10] = bm: constant over softmax axis -> dropped

    float* out  = (float*)d_out;
    float* wsf  = (float*)d_ws;
    float* hmp  = wsf;                            // [256*64] f32 block partials
    float* wmix = hmp + NBLK * Pn;                // [64*64]
    float* bmix = wmix + Bn * HEADSn * Pn;        // [64]
    float* scbc = bmix + 64;                      // [128]
    short* w1s  = (short*)(scbc + 128);           // [64*256] bf16 pre-swizzled
    short* hg   = w1s + Pn * Cn;                  // [16*9216*64] bf16

    k0_prep<<<dim3(8), dim3(256), 0, stream>>>(w1, b1, gamma, beta, mean, var, scbc, w1s);
    k1_gemm<<<dim3(NBLK), dim3(256), 0, stream>>>(x, w1s, scbc, wm, hmp, hg);
    k2_mask<<<dim3(Bn * HEADSn), dim3(256), 0, stream>>>(hmp, w2, b2, wm, wmix, bmix);
    k3_stream<<<dim3(NTILE / 1), dim3(256), 0, stream>>>(x, hg, wmix, bmix, out);
}